// Round 8
// baseline (990.425 us; speedup 1.0000x reference)
//
#include <hip/hip_runtime.h>
#include <cstddef>

// ---------------------------------------------------------------------------
// GAT 3-layer pipeline, round 8.
// - GEMM: barrier-free register GEMM. No LDS staging: A/B MFMA fragments are
//   loaded straight from global (B is L2-resident, A L2-reused via XCD
//   swizzle), software-pipelined depth-2. R7 showed the staged version was
//   latency-bound (MfmaUtil 17%, VALU 21%, 62% stall) -- not HBM-bound.
// - attention scalars: act @ (W.att) via fold_att + attdot (proven numerics).
// - Aggregation: wave-per-node, single pass (global-amax softmax bound).
// ---------------------------------------------------------------------------

typedef __bf16 bf16x8 __attribute__((ext_vector_type(8)));
typedef float floatx4 __attribute__((ext_vector_type(4)));

__device__ __forceinline__ unsigned short bf16_rn(float f) {
    unsigned int u = __float_as_uint(f);
    u += 0x7FFF + ((u >> 16) & 1);
    return (unsigned short)(u >> 16);
}
__device__ __forceinline__ float bf16_tof(unsigned short h) {
    return __uint_as_float(((unsigned int)h) << 16);
}

// ---------------- CSR build ----------------

__global__ void degree_kernel(const int* __restrict__ dst, int* __restrict__ deg, int E) {
    int e = blockIdx.x * 256 + threadIdx.x;
    if (e < E) atomicAdd(&deg[dst[e]], 1);
}

__global__ __launch_bounds__(1024) void scan_kernel(const int* __restrict__ deg,
                                                    int* __restrict__ off, int n) {
    __shared__ int wsum[16];
    __shared__ int carry_s;
    int tid = threadIdx.x, lane = tid & 63, wid = tid >> 6;
    if (tid == 0) { carry_s = 0; off[0] = 0; }
    __syncthreads();
    for (int base = 0; base < n; base += 1024) {
        int i = base + tid;
        int v = (i < n) ? deg[i] : 0;
        int s = v;
        #pragma unroll
        for (int d = 1; d < 64; d <<= 1) {
            int t = __shfl_up(s, d, 64);
            if (lane >= d) s += t;
        }
        if (lane == 63) wsum[wid] = s;
        __syncthreads();
        if (wid == 0) {
            int wv = (lane < 16) ? wsum[lane] : 0;
            #pragma unroll
            for (int d = 1; d < 16; d <<= 1) {
                int t = __shfl_up(wv, d, 64);
                if (lane >= d) wv += t;
            }
            if (lane < 16) wsum[lane] = wv;
        }
        __syncthreads();
        int prev = (wid > 0) ? wsum[wid - 1] : 0;
        int inc = carry_s + prev + s;
        if (i < n) off[i + 1] = inc;
        int chunk_total = wsum[15];
        __syncthreads();
        if (tid == 0) carry_s += chunk_total;
        __syncthreads();
    }
}

__global__ void scatter_kernel(const int* __restrict__ src, const int* __restrict__ dst,
                               const int* __restrict__ off, int* __restrict__ cursor,
                               int* __restrict__ csrc, int E) {
    int e = blockIdx.x * 256 + threadIdx.x;
    if (e < E) {
        int d = dst[e];
        int p = off[d] + atomicAdd(&cursor[d], 1);
        csrc[p] = src[e];
    }
}

// ---------------- conversions ----------------

__global__ void convert_split_kernel(const float* __restrict__ in,
                                     ushort* __restrict__ hi, ushort* __restrict__ lo,
                                     int n4) {
    int i = blockIdx.x * 256 + threadIdx.x;
    if (i >= n4) return;
    float4 v = ((const float4*)in)[i];
    ushort4 h, l;
    h.x = bf16_rn(v.x); l.x = bf16_rn(v.x - bf16_tof(h.x));
    h.y = bf16_rn(v.y); l.y = bf16_rn(v.y - bf16_tof(h.y));
    h.z = bf16_rn(v.z); l.z = bf16_rn(v.z - bf16_tof(h.z));
    h.w = bf16_rn(v.w); l.w = bf16_rn(v.w - bf16_tof(h.w));
    ((ushort4*)hi)[i] = h;
    ((ushort4*)lo)[i] = l;
}

// W fp32 [K,Ncols] -> transposed bf16 hi/lo at rows [roff, roff+Ncols) of Bcat[*,K]
__global__ void convert_w_kernel(const float* __restrict__ W,
                                 ushort* __restrict__ Th, ushort* __restrict__ Tl,
                                 int K, int Ncols, int roff) {
    int idx = blockIdx.x * 256 + threadIdx.x;
    if (idx >= K * Ncols) return;
    int k = idx / Ncols, n = idx - k * Ncols;
    float v = W[idx];
    unsigned short h = bf16_rn(v);
    Th[(size_t)(n + roff) * K + k] = h;
    Tl[(size_t)(n + roff) * K + k] = bf16_rn(v - bf16_tof(h));
}

// fold attention vectors through W
__global__ void fold_att_kernel(const float* __restrict__ W,
                                const float* __restrict__ as_, const float* __restrict__ ad_,
                                float* __restrict__ vsd, int K, int C, int H) {
    int idx = blockIdx.x * 256 + threadIdx.x;
    if (idx >= K * H) return;
    int k = idx / H, hh = idx - k * H;
    const float* wp = W + (size_t)k * (H * C) + hh * C;
    float s = 0.f, d = 0.f;
    for (int c = 0; c < C; c++) {
        float w = wp[c];
        s += w * as_[hh * C + c];
        d += w * ad_[hh * C + c];
    }
    vsd[k * 2 * H + hh] = s;
    vsd[k * 2 * H + H + hh] = d;
}

// attention scalars: asrc/adst [N,4] = act(fp32 from hi/lo) @ vsd[256, 8]
__global__ __launch_bounds__(256) void attdot_kernel(
    const ushort* __restrict__ act_hi, const ushort* __restrict__ act_lo,
    const float* __restrict__ vsd,
    float* __restrict__ asrc, float* __restrict__ adst, int n)
{
    __shared__ float vs[8 * 256];
    int tid = threadIdx.x;
    for (int i = tid; i < 2048; i += 256) vs[(i & 7) * 256 + (i >> 3)] = vsd[i];
    __syncthreads();
    int wid = tid >> 6, lane = tid & 63;
    int node = blockIdx.x * 4 + wid;
    if (node >= n) return;
    const ushort* ph = act_hi + (size_t)node * 256;
    const ushort* pl = act_lo + (size_t)node * 256;
    float acc[8] = {};
    #pragma unroll
    for (int t = 0; t < 4; t++) {
        int c = lane + t * 64;
        float v = bf16_tof(ph[c]) + bf16_tof(pl[c]);
        #pragma unroll
        for (int j = 0; j < 8; j++) acc[j] += v * vs[j * 256 + c];
    }
    #pragma unroll
    for (int o = 32; o > 0; o >>= 1)
        #pragma unroll
        for (int j = 0; j < 8; j++) acc[j] += __shfl_down(acc[j], o, 64);
    if (lane == 0) {
        #pragma unroll
        for (int j = 0; j < 4; j++) asrc[node * 4 + j] = acc[j];
        #pragma unroll
        for (int j = 0; j < 4; j++) adst[node * 4 + j] = acc[4 + j];
    }
}

// per-head global max of asrc (order-preserving uint encoding)
__global__ __launch_bounds__(256) void amax_kernel(const float* __restrict__ asrc,
                                                   unsigned int* __restrict__ amax, int n) {
    int tid = threadIdx.x;
    float4 m4 = make_float4(-1e30f, -1e30f, -1e30f, -1e30f);
    for (int i = blockIdx.x * 256 + tid; i < n; i += gridDim.x * 256) {
        float4 v = ((const float4*)asrc)[i];
        m4.x = fmaxf(m4.x, v.x); m4.y = fmaxf(m4.y, v.y);
        m4.z = fmaxf(m4.z, v.z); m4.w = fmaxf(m4.w, v.w);
    }
    #pragma unroll
    for (int o = 32; o > 0; o >>= 1) {
        m4.x = fmaxf(m4.x, __shfl_down(m4.x, o, 64));
        m4.y = fmaxf(m4.y, __shfl_down(m4.y, o, 64));
        m4.z = fmaxf(m4.z, __shfl_down(m4.z, o, 64));
        m4.w = fmaxf(m4.w, __shfl_down(m4.w, o, 64));
    }
    __shared__ float sm[4][4];
    int wid = tid >> 6, lane = tid & 63;
    if (lane == 0) { sm[wid][0] = m4.x; sm[wid][1] = m4.y; sm[wid][2] = m4.z; sm[wid][3] = m4.w; }
    __syncthreads();
    if (tid < 4) {
        float v = fmaxf(fmaxf(sm[0][tid], sm[1][tid]), fmaxf(sm[2][tid], sm[3][tid]));
        unsigned int u = __float_as_uint(v);
        u = (u >> 31) ? ~u : (u | 0x80000000u);
        atomicMax(&amax[tid], u);
    }
}

__device__ __forceinline__ float amax_decode(unsigned int u) {
    unsigned int bits = (u >> 31) ? (u & 0x7FFFFFFFu) : ~u;
    return __uint_as_float(bits);
}

// ---------------- register MFMA GEMM: [O1 | O2] = A[MxK] * Bcat^T ------------
// BM=BN=128, 4 waves (each 64x64), K=256 fixed. NO LDS, NO barriers: fragments
// loaded straight from global (dwordx4/lane), software-pipelined depth 2.
// 1D grid, XCD-swizzled: bid -> (xcd=bid&7, ny fastest, row-group) for A reuse
// in the per-XCD L2.

__global__ __launch_bounds__(256, 2) void gemm_mfma_kernel(
    const ushort* __restrict__ Ah, const ushort* __restrict__ Al,
    const ushort* __restrict__ Bh, const ushort* __restrict__ Bl,
    ushort* __restrict__ O1, int n1, ushort* __restrict__ O2,
    const float* __restrict__ bias2,
    int gm, int M, int N)
{
    const int K = 256;  // all layers: K = 256
    int gy = N >> 7;
    int bid = blockIdx.x;
    int k8 = bid & 7, s = bid >> 3;
    int ny = s % gy, bxi = s / gy;
    int bx = bxi * 8 + k8;
    if (bx >= gm) return;
    int bm = bx * 128;
    int bn = ny * 128;

    int tid = threadIdx.x;
    int lane = tid & 63, wv = tid >> 6;
    int wm = (wv >> 1) * 64;
    int wn = (wv & 1) * 64;
    int fr = lane & 15;
    int q  = lane >> 4;

    // fragment base pointers (k-offset q*8 folded in)
    const ushort *pAh[4], *pAl[4], *pBh[4], *pBl[4];
    #pragma unroll
    for (int i = 0; i < 4; ++i) {
        int ra = bm + wm + i * 16 + fr;
        if (ra > M - 1) ra = M - 1;          // clamp: no OOB reads
        pAh[i] = Ah + (size_t)ra * K + q * 8;
        pAl[i] = Al + (size_t)ra * K + q * 8;
        int rb = bn + wn + i * 16 + fr;      // always < N
        pBh[i] = Bh + (size_t)rb * K + q * 8;
        pBl[i] = Bl + (size_t)rb * K + q * 8;
    }

    floatx4 acc[4][4] = {};
    bf16x8 cah[4], cal[4], cbh[4], cbl[4];
    bf16x8 nah[4], nal[4], nbh[4], nbl[4];

    #pragma unroll
    for (int i = 0; i < 4; ++i) {
        cah[i] = *(const bf16x8*)(pAh[i]);
        cal[i] = *(const bf16x8*)(pAl[i]);
        cbh[i] = *(const bf16x8*)(pBh[i]);
        cbl[i] = *(const bf16x8*)(pBl[i]);
    }

    #pragma unroll
    for (int it = 0; it < 8; ++it) {
        int koff = (it + 1) * 32;
        if (it < 7) {
            #pragma unroll
            for (int i = 0; i < 4; ++i) {
                nah[i] = *(const bf16x8*)(pAh[i] + koff);
                nal[i] = *(const bf16x8*)(pAl[i] + koff);
                nbh[i] = *(const bf16x8*)(pBh[i] + koff);
                nbl[i] = *(const bf16x8*)(pBl[i] + koff);
            }
        }
        #pragma unroll
        for (int i = 0; i < 4; ++i)
            #pragma unroll
            for (int j = 0; j < 4; ++j) {
                acc[i][j] = __builtin_amdgcn_mfma_f32_16x16x32_bf16(cah[i], cbh[j], acc[i][j], 0, 0, 0);
                acc[i][j] = __builtin_amdgcn_mfma_f32_16x16x32_bf16(cah[i], cbl[j], acc[i][j], 0, 0, 0);
                acc[i][j] = __builtin_amdgcn_mfma_f32_16x16x32_bf16(cal[i], cbh[j], acc[i][j], 0, 0, 0);
            }
        if (it < 7) {
            #pragma unroll
            for (int i = 0; i < 4; ++i) {
                cah[i] = nah[i]; cal[i] = nal[i];
                cbh[i] = nbh[i]; cbl[i] = nbl[i];
            }
        }
    }

    // ---- C store (C/D layout: col=lane&15, row=(lane>>4)*4+reg) ----
    int n2 = N - n1;
    #pragma unroll
    for (int i = 0; i < 4; ++i) {
        #pragma unroll
        for (int r = 0; r < 4; ++r) {
            int grow = bm + wm + i * 16 + q * 4 + r;
            if (grow < M) {
                #pragma unroll
                for (int j = 0; j < 4; ++j) {
                    int gcol = bn + wn + j * 16 + fr;
                    float v = acc[i][j][r];
                    if (gcol < n1) {
                        O1[(size_t)grow * n1 + gcol] = bf16_rn(v);
                    } else {
                        v += bias2[gcol - n1];
                        O2[(size_t)grow * n2 + (gcol - n1)] = bf16_rn(v);
                    }
                }
            }
        }
    }
}

// ---------------- aggregation layers 0/1: wave-per-node, single pass ---------

__global__ __launch_bounds__(256) void agg01_kernel(
    const ushort* __restrict__ h,    // [N,256] bf16
    const float* __restrict__ asrc, const float* __restrict__ adst,
    const unsigned int* __restrict__ amax,  // [4] encoded
    const int* __restrict__ off, const int* __restrict__ csrc,
    const ushort* __restrict__ lin,  // [N,256] bf16 (lb applied in GEMM)
    const float* __restrict__ bias,  // [256]
    ushort* __restrict__ out_hi, ushort* __restrict__ out_lo,
    int n)
{
    int wid = threadIdx.x >> 6, lane = threadIdx.x & 63;
    int d = blockIdx.x * 4 + wid;
    if (d >= n) return;
    int head = lane >> 4;
    int c0 = lane * 4;
    float a_d = adst[d * 4 + head];
    float mh = amax_decode(amax[head]) + a_d;
    float m = (mh > 0.f) ? mh : 0.2f * mh;   // >= true segment max
    int s0 = off[d], s1 = off[d + 1];

    float denom = 0.f, a0 = 0.f, a1 = 0.f, a2 = 0.f, a3 = 0.f;
    for (int i = s0; i < s1; ++i) {
        int s = csrc[i];
        float e = asrc[s * 4 + head] + a_d;
        e = (e > 0.f) ? e : 0.2f * e;
        float w = __expf(e - m);
        denom += w;
        ushort4 hv = *(const ushort4*)(h + (size_t)s * 256 + c0);
        a0 += w * bf16_tof(hv.x);
        a1 += w * bf16_tof(hv.y);
        a2 += w * bf16_tof(hv.z);
        a3 += w * bf16_tof(hv.w);
    }
    float inv = 1.f / (denom + 1e-16f);
    float4 b4 = *(const float4*)(bias + c0);
    ushort4 l4 = *(const ushort4*)(lin + (size_t)d * 256 + c0);
    float v0 = a0 * inv + b4.x + bf16_tof(l4.x);
    float v1 = a1 * inv + b4.y + bf16_tof(l4.y);
    float v2 = a2 * inv + b4.z + bf16_tof(l4.z);
    float v3 = a3 * inv + b4.w + bf16_tof(l4.w);
    v0 = (v0 > 0.f) ? v0 : (__expf(v0) - 1.f);
    v1 = (v1 > 0.f) ? v1 : (__expf(v1) - 1.f);
    v2 = (v2 > 0.f) ? v2 : (__expf(v2) - 1.f);
    v3 = (v3 > 0.f) ? v3 : (__expf(v3) - 1.f);
    ushort4 oh, ol;
    oh.x = bf16_rn(v0); ol.x = bf16_rn(v0 - bf16_tof(oh.x));
    oh.y = bf16_rn(v1); ol.y = bf16_rn(v1 - bf16_tof(oh.y));
    oh.z = bf16_rn(v2); ol.z = bf16_rn(v2 - bf16_tof(oh.z));
    oh.w = bf16_rn(v3); ol.w = bf16_rn(v3 - bf16_tof(oh.w));
    *(ushort4*)(out_hi + (size_t)d * 256 + c0) = oh;
    *(ushort4*)(out_lo + (size_t)d * 256 + c0) = ol;
}

// ---------------- aggregation layer 2: wave-per-node, mean heads -------------

__global__ __launch_bounds__(256) void agg2_kernel(
    const ushort* __restrict__ h,    // [N,512] bf16
    const float* __restrict__ asrc, const float* __restrict__ adst,
    const unsigned int* __restrict__ amax,
    const int* __restrict__ off, const int* __restrict__ csrc,
    const ushort* __restrict__ lin,  // [N,128] bf16 (lb2 applied in GEMM)
    const float* __restrict__ bias,  // [128]
    float* __restrict__ out,         // [N,128]
    int n)
{
    int wid = threadIdx.x >> 6, lane = threadIdx.x & 63;
    int d = blockIdx.x * 4 + wid;
    if (d >= n) return;
    int ha = lane >> 5;
    int hb = ha + 2;
    int c0 = lane * 4;
    float ad_a = adst[d * 4 + ha];
    float ad_b = adst[d * 4 + hb];
    float mha = amax_decode(amax[ha]) + ad_a;
    float mhb = amax_decode(amax[hb]) + ad_b;
    float ma = (mha > 0.f) ? mha : 0.2f * mha;
    float mb = (mhb > 0.f) ? mhb : 0.2f * mhb;
    int s0 = off[d], s1 = off[d + 1];

    float da = 0.f, db = 0.f;
    floatx4 aa = {0.f, 0.f, 0.f, 0.f}, ab = {0.f, 0.f, 0.f, 0.f};
    for (int i = s0; i < s1; ++i) {
        int s = csrc[i];
        float ea = asrc[s * 4 + ha] + ad_a;
        float eb = asrc[s * 4 + hb] + ad_b;
        ea = (ea > 0.f) ? ea : 0.2f * ea;
        eb = (eb > 0.f) ? eb : 0.2f * eb;
        float wa = __expf(ea - ma), wb = __expf(eb - mb);
        da += wa; db += wb;
        ushort4 va = *(const ushort4*)(h + (size_t)s * 512 + c0);
        ushort4 vb = *(const ushort4*)(h + (size_t)s * 512 + 256 + c0);
        aa[0] += wa * bf16_tof(va.x); aa[1] += wa * bf16_tof(va.y);
        aa[2] += wa * bf16_tof(va.z); aa[3] += wa * bf16_tof(va.w);
        ab[0] += wb * bf16_tof(vb.x); ab[1] += wb * bf16_tof(vb.y);
        ab[2] += wb * bf16_tof(vb.z); ab[3] += wb * bf16_tof(vb.w);
    }
    float ia = 1.f / (da + 1e-16f), ib = 1.f / (db + 1e-16f);
    float s4[4];
    #pragma unroll
    for (int j = 0; j < 4; ++j) s4[j] = aa[j] * ia + ab[j] * ib;
    float p4[4];
    #pragma unroll
    for (int j = 0; j < 4; ++j) p4[j] = __shfl_xor(s4[j], 32, 64);
    if (lane < 32) {
        float4 b4 = *(const float4*)(bias + c0);
        ushort4 l4 = *(const ushort4*)(lin + (size_t)d * 128 + c0);
        float4 o;
        o.x = 0.25f * (s4[0] + p4[0]) + b4.x + bf16_tof(l4.x);
        o.y = 0.25f * (s4[1] + p4[1]) + b4.y + bf16_tof(l4.y);
        o.z = 0.25f * (s4[2] + p4[2]) + b4.z + bf16_tof(l4.z);
        o.w = 0.25f * (s4[3] + p4[3]) + b4.w + bf16_tof(l4.w);
        *(float4*)(out + (size_t)d * 128 + c0) = o;
    }
}

// ---------------------------------------------------------------------------

extern "C" void kernel_launch(void* const* d_in, const int* in_sizes, int n_in,
                              void* d_out, int out_size, void* d_ws, size_t ws_size,
                              hipStream_t stream)
{
    const float* x   = (const float*)d_in[0];
    const int*   ei  = (const int*)d_in[1];
    const float* W0  = (const float*)d_in[2];
    const float* as0 = (const float*)d_in[3];
    const float* ad0 = (const float*)d_in[4];
    const float* b0  = (const float*)d_in[5];
    const float* lw0 = (const float*)d_in[6];
    const float* lb0 = (const float*)d_in[7];
    const float* W1  = (const float*)d_in[8];
    const float* as1 = (const float*)d_in[9];
    const float* ad1 = (const float*)d_in[10];
    const float* b1  = (const float*)d_in[11];
    const float* lw1 = (const float*)d_in[12];
    const float* lb1 = (const float*)d_in[13];
    const float* W2  = (const float*)d_in[14];
    const float* as2 = (const float*)d_in[15];
    const float* ad2 = (const float*)d_in[16];
    const float* b2  = (const float*)d_in[17];
    const float* lw2 = (const float*)d_in[18];
    const float* lb2 = (const float*)d_in[19];
    float* out = (float*)d_out;

    const int N = in_sizes[0] / 256;
    const int E = in_sizes[1] / 2;
    const int* esrc = ei;
    const int* edst = ei + E;

    // ---- workspace layout ----
    char* p = (char*)d_ws;
    ushort* act_hi = (ushort*)p; p += (size_t)N * 256 * 2;
    ushort* act_lo = (ushort*)p; p += (size_t)N * 256 * 2;
    ushort* h      = (ushort*)p; p += (size_t)N * 512 * 2;
    ushort* lin    = (ushort*)p; p += (size_t)N * 256 * 2;
    float*  asrc   = (float*)p;  p += (size_t)N * 4 * 4;
    float*  adst   = (float*)p;  p += (size_t)N * 4 * 4;
    ushort* B0h = (ushort*)p; p += (size_t)512 * 256 * 2;
    ushort* B0l = (ushort*)p; p += (size_t)512 * 256 * 2;
    ushort* B1h = (ushort*)p; p += (size_t)512 * 256 * 2;
    ushort* B1l = (ushort*)p; p += (size_t)512 * 256 * 2;
    ushort* B2h = (ushort*)p; p += (size_t)640 * 256 * 2;
    ushort* B2l = (ushort*)p; p += (size_t)640 * 256 * 2;
    float* vsd0 = (float*)p; p += 256 * 8 * 4;
    float* vsd1 = (float*)p; p += 256 * 8 * 4;
    float* vsd2 = (float*)p; p += 256 * 8 * 4;
    unsigned int* amax = (unsigned int*)p;      // 12 slots (4 per layer)
    int* deg    = (int*)(amax + 12);
    int* off    = deg + N;
    int* cursor = off + N + 1;
    int* csrc   = cursor + N;

    // ---- zero amax + deg + off + cursor in one memset ----
    hipMemsetAsync(amax, 0, sizeof(int) * (size_t)(3 * N + 13), stream);

    // ---- CSR build ----
    int egrid = (E + 255) / 256;
    degree_kernel<<<egrid, 256, 0, stream>>>(edst, deg, E);
    scan_kernel<<<1, 1024, 0, stream>>>(deg, off, N);
    scatter_kernel<<<egrid, 256, 0, stream>>>(esrc, edst, off, cursor, csrc, E);

    // ---- weight prep ----
    int wg64k = (256 * 256 + 255) / 256;
    convert_w_kernel<<<wg64k, 256, 0, stream>>>(W0,  B0h, B0l, 256, 256, 0);
    convert_w_kernel<<<wg64k, 256, 0, stream>>>(lw0, B0h, B0l, 256, 256, 256);
    convert_w_kernel<<<wg64k, 256, 0, stream>>>(W1,  B1h, B1l, 256, 256, 0);
    convert_w_kernel<<<wg64k, 256, 0, stream>>>(lw1, B1h, B1l, 256, 256, 256);
    convert_w_kernel<<<2 * wg64k, 256, 0, stream>>>(W2, B2h, B2l, 256, 512, 0);
    convert_w_kernel<<<(256 * 128 + 255) / 256, 256, 0, stream>>>(lw2, B2h, B2l, 256, 128, 512);
    fold_att_kernel<<<4, 256, 0, stream>>>(W0, as0, ad0, vsd0, 256, 64, 4);
    fold_att_kernel<<<4, 256, 0, stream>>>(W1, as1, ad1, vsd1, 256, 64, 4);
    fold_att_kernel<<<4, 256, 0, stream>>>(W2, as2, ad2, vsd2, 256, 128, 4);

    // ---- x -> bf16 hi/lo ----
    int n4 = N * 256 / 4;
    convert_split_kernel<<<(n4 + 255) / 256, 256, 0, stream>>>(x, act_hi, act_lo, n4);

    int gm = (N + 127) / 128;            // 391
    int gmp = ((gm + 7) / 8) * 8;        // padded to XCD multiple
    int g4 = (N + 3) / 4;

    // ---- layer 0 ----
    gemm_mfma_kernel<<<gmp * 4, 256, 0, stream>>>(act_hi, act_lo, B0h, B0l, h, 256, lin, lb0, gm, N, 512);
    attdot_kernel<<<g4, 256, 0, stream>>>(act_hi, act_lo, vsd0, asrc, adst, N);
    amax_kernel<<<32, 256, 0, stream>>>(asrc, amax + 0, N);
    agg01_kernel<<<g4, 256, 0, stream>>>(h, asrc, adst, amax + 0, off, csrc, lin, b0, act_hi, act_lo, N);

    // ---- layer 1 ----
    gemm_mfma_kernel<<<gmp * 4, 256, 0, stream>>>(act_hi, act_lo, B1h, B1l, h, 256, lin, lb1, gm, N, 512);
    attdot_kernel<<<g4, 256, 0, stream>>>(act_hi, act_lo, vsd1, asrc, adst, N);
    amax_kernel<<<32, 256, 0, stream>>>(asrc, amax + 4, N);
    agg01_kernel<<<g4, 256, 0, stream>>>(h, asrc, adst, amax + 4, off, csrc, lin, b1, act_hi, act_lo, N);

    // ---- layer 2 ----
    gemm_mfma_kernel<<<gmp * 5, 256, 0, stream>>>(act_hi, act_lo, B2h, B2l, h, 512, lin, lb2, gm, N, 640);
    attdot_kernel<<<g4, 256, 0, stream>>>(act_hi, act_lo, vsd2, asrc, adst, N);
    amax_kernel<<<32, 256, 0, stream>>>(asrc, amax + 8, N);
    agg2_kernel<<<g4, 256, 0, stream>>>(h, asrc, adst, amax + 8, off, csrc, lin, b2, out, N);
}

// Round 9
// 769.644 us; speedup vs baseline: 1.2869x; 1.2869x over previous
//
#include <hip/hip_runtime.h>
#include <cstddef>

// ---------------------------------------------------------------------------
// GAT 3-layer pipeline, round 9.
// - GEMM: barrier-free register MFMA GEMM on FRAGMENT-PACKED operands:
//   every frag load = one contiguous 1KB wave load (R8's 16-line strided
//   loads were the address-pipe bottleneck). XCD-swizzled grid kept.
// - Packing producers: wprep (weights, merged 1 kernel), split_att (x),
//   agg01 epilogue (act) which also computes next-layer attn dots (fp32,
//   act-derived = proven numerics) -> attdot kernels eliminated.
// - Aggregation: wave-per-node, single pass (global-amax softmax bound).
// Packed layout (per matrix, rows padded to 128): group g=row>>4, chunk
// c=k>>5, lane l=(row&15)+16*((k&31)>>3), sub=k&7:
//   offset = (g*8+c)*512 + l*8 + sub   (ushorts)
// ---------------------------------------------------------------------------

typedef __bf16 bf16x8 __attribute__((ext_vector_type(8)));
typedef float floatx4 __attribute__((ext_vector_type(4)));

__device__ __forceinline__ unsigned short bf16_rn(float f) {
    unsigned int u = __float_as_uint(f);
    u += 0x7FFF + ((u >> 16) & 1);
    return (unsigned short)(u >> 16);
}
__device__ __forceinline__ float bf16_tof(unsigned short h) {
    return __uint_as_float(((unsigned int)h) << 16);
}

// ---------------- CSR build ----------------

__global__ void degree_kernel(const int* __restrict__ dst, int* __restrict__ deg, int E) {
    int e = blockIdx.x * 256 + threadIdx.x;
    if (e < E) atomicAdd(&deg[dst[e]], 1);
}

__global__ __launch_bounds__(1024) void scan_kernel(const int* __restrict__ deg,
                                                    int* __restrict__ off, int n) {
    __shared__ int wsum[16];
    __shared__ int carry_s;
    int tid = threadIdx.x, lane = tid & 63, wid = tid >> 6;
    if (tid == 0) { carry_s = 0; off[0] = 0; }
    __syncthreads();
    for (int base = 0; base < n; base += 1024) {
        int i = base + tid;
        int v = (i < n) ? deg[i] : 0;
        int s = v;
        #pragma unroll
        for (int d = 1; d < 64; d <<= 1) {
            int t = __shfl_up(s, d, 64);
            if (lane >= d) s += t;
        }
        if (lane == 63) wsum[wid] = s;
        __syncthreads();
        if (wid == 0) {
            int wv = (lane < 16) ? wsum[lane] : 0;
            #pragma unroll
            for (int d = 1; d < 16; d <<= 1) {
                int t = __shfl_up(wv, d, 64);
                if (lane >= d) wv += t;
            }
            if (lane < 16) wsum[lane] = wv;
        }
        __syncthreads();
        int prev = (wid > 0) ? wsum[wid - 1] : 0;
        int inc = carry_s + prev + s;
        if (i < n) off[i + 1] = inc;
        int chunk_total = wsum[15];
        __syncthreads();
        if (tid == 0) carry_s += chunk_total;
        __syncthreads();
    }
}

__global__ void scatter_kernel(const int* __restrict__ src, const int* __restrict__ dst,
                               const int* __restrict__ off, int* __restrict__ cursor,
                               int* __restrict__ csrc, int E) {
    int e = blockIdx.x * 256 + threadIdx.x;
    if (e < E) {
        int d = dst[e];
        int p = off[d] + atomicAdd(&cursor[d], 1);
        csrc[p] = src[e];
    }
}

// ---------------- merged weight prep: 6 packed converts + 3 att folds -------

__global__ __launch_bounds__(256) void wprep_kernel(
    const float* __restrict__ W0, const float* __restrict__ lw0,
    const float* __restrict__ W1, const float* __restrict__ lw1,
    const float* __restrict__ W2, const float* __restrict__ lw2,
    ushort* __restrict__ B0h, ushort* __restrict__ B0l,
    ushort* __restrict__ B1h, ushort* __restrict__ B1l,
    ushort* __restrict__ B2h, ushort* __restrict__ B2l,
    const float* __restrict__ as0, const float* __restrict__ ad0,
    const float* __restrict__ as1, const float* __restrict__ ad1,
    const float* __restrict__ as2, const float* __restrict__ ad2,
    float* __restrict__ vsd0, float* __restrict__ vsd1, float* __restrict__ vsd2)
{
    int bid = blockIdx.x, tid = threadIdx.x;
    if (bid < 1664) {
        const float* src; ushort* dh; ushort* dl; int Ncols, roff, base;
        if (bid < 256)       { src = W0;  dh = B0h; dl = B0l; Ncols = 256; roff = 0;   base = 0; }
        else if (bid < 512)  { src = lw0; dh = B0h; dl = B0l; Ncols = 256; roff = 256; base = 256; }
        else if (bid < 768)  { src = W1;  dh = B1h; dl = B1l; Ncols = 256; roff = 0;   base = 512; }
        else if (bid < 1024) { src = lw1; dh = B1h; dl = B1l; Ncols = 256; roff = 256; base = 768; }
        else if (bid < 1536) { src = W2;  dh = B2h; dl = B2l; Ncols = 512; roff = 0;   base = 1024; }
        else                 { src = lw2; dh = B2h; dl = B2l; Ncols = 128; roff = 512; base = 1536; }
        int idx = (bid - base) * 256 + tid;
        int k = idx / Ncols, n = idx - k * Ncols;
        float v = src[idx];
        unsigned short hi = bf16_rn(v);
        unsigned short lo = bf16_rn(v - bf16_tof(hi));
        int row = n + roff;
        int poff = ((row >> 4) * 8 + (k >> 5)) * 512 + (((row & 15) + 16 * ((k & 31) >> 3)) << 3) + (k & 7);
        dh[poff] = hi;
        dl[poff] = lo;
    } else {
        int fj = (bid - 1664) >> 2;
        int idx = ((bid - 1664) & 3) * 256 + tid;   // 0..1023 = K*H
        const float *W, *as_, *ad_; float* vsd; int C;
        if (fj == 0)      { W = W0; as_ = as0; ad_ = ad0; vsd = vsd0; C = 64; }
        else if (fj == 1) { W = W1; as_ = as1; ad_ = ad1; vsd = vsd1; C = 64; }
        else              { W = W2; as_ = as2; ad_ = ad2; vsd = vsd2; C = 128; }
        int k = idx >> 2, hh = idx & 3;
        const float* wp = W + (size_t)k * (4 * C) + hh * C;
        float s = 0.f, d = 0.f;
        for (int c = 0; c < C; c++) {
            float w = wp[c];
            s += w * as_[hh * C + c];
            d += w * ad_[hh * C + c];
        }
        vsd[k * 8 + hh] = s;       // vsd layout: [k][8] = 4 src then 4 dst
        vsd[k * 8 + 4 + hh] = d;
    }
}

// ---------------- x -> packed bf16 hi/lo + layer-0 attention dots ------------

__global__ __launch_bounds__(256) void split_att_kernel(
    const float* __restrict__ x, const float* __restrict__ vsd,
    ushort* __restrict__ Aph, ushort* __restrict__ Apl,
    float* __restrict__ asrc, float* __restrict__ adst, int n)
{
    int wid = threadIdx.x >> 6, lane = threadIdx.x & 63;
    int d = blockIdx.x * 4 + wid;
    if (d >= n) return;
    int k0 = lane * 4;
    float4 v = *(const float4*)(x + (size_t)d * 256 + k0);
    ushort4 hi, lo;
    hi.x = bf16_rn(v.x); lo.x = bf16_rn(v.x - bf16_tof(hi.x));
    hi.y = bf16_rn(v.y); lo.y = bf16_rn(v.y - bf16_tof(hi.y));
    hi.z = bf16_rn(v.z); lo.z = bf16_rn(v.z - bf16_tof(hi.z));
    hi.w = bf16_rn(v.w); lo.w = bf16_rn(v.w - bf16_tof(hi.w));
    int poff = ((d >> 4) * 8 + (k0 >> 5)) * 512 + (((d & 15) + 16 * ((k0 & 31) >> 3)) << 3) + (k0 & 7);
    *(ushort4*)(Aph + poff) = hi;
    *(ushort4*)(Apl + poff) = lo;

    const float* vp = vsd + (size_t)k0 * 8;
    float4 r0a = *(const float4*)(vp + 0),  r0b = *(const float4*)(vp + 4);
    float4 r1a = *(const float4*)(vp + 8),  r1b = *(const float4*)(vp + 12);
    float4 r2a = *(const float4*)(vp + 16), r2b = *(const float4*)(vp + 20);
    float4 r3a = *(const float4*)(vp + 24), r3b = *(const float4*)(vp + 28);
    float4 pa, pb;
    pa.x = v.x * r0a.x + v.y * r1a.x + v.z * r2a.x + v.w * r3a.x;
    pa.y = v.x * r0a.y + v.y * r1a.y + v.z * r2a.y + v.w * r3a.y;
    pa.z = v.x * r0a.z + v.y * r1a.z + v.z * r2a.z + v.w * r3a.z;
    pa.w = v.x * r0a.w + v.y * r1a.w + v.z * r2a.w + v.w * r3a.w;
    pb.x = v.x * r0b.x + v.y * r1b.x + v.z * r2b.x + v.w * r3b.x;
    pb.y = v.x * r0b.y + v.y * r1b.y + v.z * r2b.y + v.w * r3b.y;
    pb.z = v.x * r0b.z + v.y * r1b.z + v.z * r2b.z + v.w * r3b.z;
    pb.w = v.x * r0b.w + v.y * r1b.w + v.z * r2b.w + v.w * r3b.w;
    #pragma unroll
    for (int o = 1; o < 64; o <<= 1) {
        pa.x += __shfl_xor(pa.x, o, 64); pa.y += __shfl_xor(pa.y, o, 64);
        pa.z += __shfl_xor(pa.z, o, 64); pa.w += __shfl_xor(pa.w, o, 64);
        pb.x += __shfl_xor(pb.x, o, 64); pb.y += __shfl_xor(pb.y, o, 64);
        pb.z += __shfl_xor(pb.z, o, 64); pb.w += __shfl_xor(pb.w, o, 64);
    }
    if (lane == 0) {
        *(float4*)(asrc + (size_t)d * 4) = pa;
        *(float4*)(adst + (size_t)d * 4) = pb;
    }
}

// per-head global max of asrc (order-preserving uint encoding)
__global__ __launch_bounds__(256) void amax_kernel(const float* __restrict__ asrc,
                                                   unsigned int* __restrict__ amax, int n) {
    int tid = threadIdx.x;
    float4 m4 = make_float4(-1e30f, -1e30f, -1e30f, -1e30f);
    for (int i = blockIdx.x * 256 + tid; i < n; i += gridDim.x * 256) {
        float4 v = ((const float4*)asrc)[i];
        m4.x = fmaxf(m4.x, v.x); m4.y = fmaxf(m4.y, v.y);
        m4.z = fmaxf(m4.z, v.z); m4.w = fmaxf(m4.w, v.w);
    }
    #pragma unroll
    for (int o = 32; o > 0; o >>= 1) {
        m4.x = fmaxf(m4.x, __shfl_down(m4.x, o, 64));
        m4.y = fmaxf(m4.y, __shfl_down(m4.y, o, 64));
        m4.z = fmaxf(m4.z, __shfl_down(m4.z, o, 64));
        m4.w = fmaxf(m4.w, __shfl_down(m4.w, o, 64));
    }
    __shared__ float sm[4][4];
    int wid = tid >> 6, lane = tid & 63;
    if (lane == 0) { sm[wid][0] = m4.x; sm[wid][1] = m4.y; sm[wid][2] = m4.z; sm[wid][3] = m4.w; }
    __syncthreads();
    if (tid < 4) {
        float v = fmaxf(fmaxf(sm[0][tid], sm[1][tid]), fmaxf(sm[2][tid], sm[3][tid]));
        unsigned int u = __float_as_uint(v);
        u = (u >> 31) ? ~u : (u | 0x80000000u);
        atomicMax(&amax[tid], u);
    }
}

__device__ __forceinline__ float amax_decode(unsigned int u) {
    unsigned int bits = (u >> 31) ? (u & 0x7FFFFFFFu) : ~u;
    return __uint_as_float(bits);
}

// ---------------- register MFMA GEMM on packed operands ----------------------
// BM=BN=128, 4 waves (64x64 each), K=256. No LDS, no barriers. Every frag
// load is a contiguous 1KB wave load. Depth-2 software pipeline over the 8
// K-chunks. XCD-swizzled 1D grid for A L2 reuse.

__global__ __launch_bounds__(256, 2) void gemm_mfma_kernel(
    const ushort* __restrict__ Aph, const ushort* __restrict__ Apl,
    const ushort* __restrict__ Bph, const ushort* __restrict__ Bpl,
    ushort* __restrict__ O1, int n1, ushort* __restrict__ O2,
    const float* __restrict__ bias2,
    int gm, int M, int N)
{
    int gy = N >> 7;
    int bid = blockIdx.x;
    int k8 = bid & 7, sb = bid >> 3;
    int ny = sb % gy, bxi = sb / gy;
    int bx = bxi * 8 + k8;
    if (bx >= gm) return;
    int bm = bx * 128, bn = ny * 128;

    int tid = threadIdx.x, lane = tid & 63, wv = tid >> 6;
    int wm = (wv >> 1) * 64, wn = (wv & 1) * 64;
    int fr = lane & 15, q = lane >> 4;

    size_t aoff = (size_t)((bm + wm) >> 4) * 4096 + lane * 8;  // +i*4096 +c*512
    size_t boff = (size_t)((bn + wn) >> 4) * 4096 + lane * 8;

    floatx4 acc[4][4] = {};
    bf16x8 cah[4], cal[4], cbh[4], cbl[4];
    bf16x8 nah[4], nal[4], nbh[4], nbl[4];

    #pragma unroll
    for (int i = 0; i < 4; ++i) {
        cah[i] = *(const bf16x8*)(Aph + aoff + i * 4096);
        cal[i] = *(const bf16x8*)(Apl + aoff + i * 4096);
        cbh[i] = *(const bf16x8*)(Bph + boff + i * 4096);
        cbl[i] = *(const bf16x8*)(Bpl + boff + i * 4096);
    }

    #pragma unroll
    for (int it = 0; it < 8; ++it) {
        if (it < 7) {
            int co = (it + 1) * 512;
            #pragma unroll
            for (int i = 0; i < 4; ++i) {
                nah[i] = *(const bf16x8*)(Aph + aoff + i * 4096 + co);
                nal[i] = *(const bf16x8*)(Apl + aoff + i * 4096 + co);
                nbh[i] = *(const bf16x8*)(Bph + boff + i * 4096 + co);
                nbl[i] = *(const bf16x8*)(Bpl + boff + i * 4096 + co);
            }
        }
        #pragma unroll
        for (int i = 0; i < 4; ++i)
            #pragma unroll
            for (int j = 0; j < 4; ++j) {
                acc[i][j] = __builtin_amdgcn_mfma_f32_16x16x32_bf16(cah[i], cbh[j], acc[i][j], 0, 0, 0);
                acc[i][j] = __builtin_amdgcn_mfma_f32_16x16x32_bf16(cah[i], cbl[j], acc[i][j], 0, 0, 0);
                acc[i][j] = __builtin_amdgcn_mfma_f32_16x16x32_bf16(cal[i], cbh[j], acc[i][j], 0, 0, 0);
            }
        if (it < 7) {
            #pragma unroll
            for (int i = 0; i < 4; ++i) {
                cah[i] = nah[i]; cal[i] = nal[i];
                cbh[i] = nbh[i]; cbl[i] = nbl[i];
            }
        }
    }

    // ---- C store (C/D layout: col=lane&15, row=(lane>>4)*4+reg) ----
    int n2 = N - n1;
    #pragma unroll
    for (int i = 0; i < 4; ++i) {
        #pragma unroll
        for (int r = 0; r < 4; ++r) {
            int grow = bm + wm + i * 16 + q * 4 + r;
            if (grow < M) {
                #pragma unroll
                for (int j = 0; j < 4; ++j) {
                    int gcol = bn + wn + j * 16 + fr;
                    float v = acc[i][j][r];
                    if (gcol < n1) {
                        O1[(size_t)grow * n1 + gcol] = bf16_rn(v);
                    } else {
                        v += bias2[gcol - n1];
                        O2[(size_t)grow * n2 + (gcol - n1)] = bf16_rn(v);
                    }
                }
            }
        }
    }
}

// ---------------- aggregation layers 0/1: wave-per-node, single pass,
//                  packed act out + fused next-layer attention dots ----------

__global__ __launch_bounds__(256) void agg01_kernel(
    const ushort* __restrict__ h,    // [N,256] bf16
    const float* __restrict__ asrc, const float* __restrict__ adst,
    const unsigned int* __restrict__ amax,
    const int* __restrict__ off, const int* __restrict__ csrc,
    const ushort* __restrict__ lin,  // [N,256] bf16 (lb applied in GEMM)
    const float* __restrict__ bias,  // [256]
    ushort* __restrict__ Aph, ushort* __restrict__ Apl,   // packed act out
    const float* __restrict__ vsd_next,                   // [256][8]
    float* __restrict__ asrc_out, float* __restrict__ adst_out,
    int n)
{
    int wid = threadIdx.x >> 6, lane = threadIdx.x & 63;
    int d = blockIdx.x * 4 + wid;
    if (d >= n) return;
    int head = lane >> 4;
    int c0 = lane * 4;
    float a_d = adst[d * 4 + head];
    float mh = amax_decode(amax[head]) + a_d;
    float m = (mh > 0.f) ? mh : 0.2f * mh;   // >= true segment max
    int s0 = off[d], s1 = off[d + 1];

    float denom = 0.f, a0 = 0.f, a1 = 0.f, a2 = 0.f, a3 = 0.f;
    for (int i = s0; i < s1; ++i) {
        int s = csrc[i];
        float e = asrc[s * 4 + head] + a_d;
        e = (e > 0.f) ? e : 0.2f * e;
        float w = __expf(e - m);
        denom += w;
        ushort4 hv = *(const ushort4*)(h + (size_t)s * 256 + c0);
        a0 += w * bf16_tof(hv.x);
        a1 += w * bf16_tof(hv.y);
        a2 += w * bf16_tof(hv.z);
        a3 += w * bf16_tof(hv.w);
    }
    float inv = 1.f / (denom + 1e-16f);
    float4 b4 = *(const float4*)(bias + c0);
    ushort4 l4 = *(const ushort4*)(lin + (size_t)d * 256 + c0);
    float v0 = a0 * inv + b4.x + bf16_tof(l4.x);
    float v1 = a1 * inv + b4.y + bf16_tof(l4.y);
    float v2 = a2 * inv + b4.z + bf16_tof(l4.z);
    float v3 = a3 * inv + b4.w + bf16_tof(l4.w);
    v0 = (v0 > 0.f) ? v0 : (__expf(v0) - 1.f);   // ELU
    v1 = (v1 > 0.f) ? v1 : (__expf(v1) - 1.f);
    v2 = (v2 > 0.f) ? v2 : (__expf(v2) - 1.f);
    v3 = (v3 > 0.f) ? v3 : (__expf(v3) - 1.f);

    // packed act write
    ushort4 oh, ol;
    oh.x = bf16_rn(v0); ol.x = bf16_rn(v0 - bf16_tof(oh.x));
    oh.y = bf16_rn(v1); ol.y = bf16_rn(v1 - bf16_tof(oh.y));
    oh.z = bf16_rn(v2); ol.z = bf16_rn(v2 - bf16_tof(oh.z));
    oh.w = bf16_rn(v3); ol.w = bf16_rn(v3 - bf16_tof(oh.w));
    int poff = ((d >> 4) * 8 + (c0 >> 5)) * 512 + (((d & 15) + 16 * ((c0 & 31) >> 3)) << 3) + (c0 & 7);
    *(ushort4*)(Aph + poff) = oh;
    *(ushort4*)(Apl + poff) = ol;

    // fused next-layer attention dots (act-derived, exact fp32 values)
    const float* vp = vsd_next + (size_t)c0 * 8;
    float4 r0a = *(const float4*)(vp + 0),  r0b = *(const float4*)(vp + 4);
    float4 r1a = *(const float4*)(vp + 8),  r1b = *(const float4*)(vp + 12);
    float4 r2a = *(const float4*)(vp + 16), r2b = *(const float4*)(vp + 20);
    float4 r3a = *(const float4*)(vp + 24), r3b = *(const float4*)(vp + 28);
    float4 pa, pb;
    pa.x = v0 * r0a.x + v1 * r1a.x + v2 * r2a.x + v3 * r3a.x;
    pa.y = v0 * r0a.y + v1 * r1a.y + v2 * r2a.y + v3 * r3a.y;
    pa.z = v0 * r0a.z + v1 * r1a.z + v2 * r2a.z + v3 * r3a.z;
    pa.w = v0 * r0a.w + v1 * r1a.w + v2 * r2a.w + v3 * r3a.w;
    pb.x = v0 * r0b.x + v1 * r1b.x + v2 * r2b.x + v3 * r3b.x;
    pb.y = v0 * r0b.y + v1 * r1b.y + v2 * r2b.y + v3 * r3b.y;
    pb.z = v0 * r0b.z + v1 * r1b.z + v2 * r2b.z + v3 * r3b.z;
    pb.w = v0 * r0b.w + v1 * r1b.w + v2 * r2b.w + v3 * r3b.w;
    #pragma unroll
    for (int o = 1; o < 64; o <<= 1) {
        pa.x += __shfl_xor(pa.x, o, 64); pa.y += __shfl_xor(pa.y, o, 64);
        pa.z += __shfl_xor(pa.z, o, 64); pa.w += __shfl_xor(pa.w, o, 64);
        pb.x += __shfl_xor(pb.x, o, 64); pb.y += __shfl_xor(pb.y, o, 64);
        pb.z += __shfl_xor(pb.z, o, 64); pb.w += __shfl_xor(pb.w, o, 64);
    }
    if (lane == 0) {
        *(float4*)(asrc_out + (size_t)d * 4) = pa;
        *(float4*)(adst_out + (size_t)d * 4) = pb;
    }
}

// ---------------- aggregation layer 2: wave-per-node, mean heads -------------

__global__ __launch_bounds__(256) void agg2_kernel(
    const ushort* __restrict__ h,    // [N,512] bf16
    const float* __restrict__ asrc, const float* __restrict__ adst,
    const unsigned int* __restrict__ amax,
    const int* __restrict__ off, const int* __restrict__ csrc,
    const ushort* __restrict__ lin,  // [N,128] bf16 (lb2 applied in GEMM)
    const float* __restrict__ bias,  // [128]
    float* __restrict__ out,         // [N,128]
    int n)
{
    int wid = threadIdx.x >> 6, lane = threadIdx.x & 63;
    int d = blockIdx.x * 4 + wid;
    if (d >= n) return;
    int ha = lane >> 5;
    int hb = ha + 2;
    int c0 = lane * 4;
    float ad_a = adst[d * 4 + ha];
    float ad_b = adst[d * 4 + hb];
    float mha = amax_decode(amax[ha]) + ad_a;
    float mhb = amax_decode(amax[hb]) + ad_b;
    float ma = (mha > 0.f) ? mha : 0.2f * mha;
    float mb = (mhb > 0.f) ? mhb : 0.2f * mhb;
    int s0 = off[d], s1 = off[d + 1];

    float da = 0.f, db = 0.f;
    floatx4 aa = {0.f, 0.f, 0.f, 0.f}, ab = {0.f, 0.f, 0.f, 0.f};
    for (int i = s0; i < s1; ++i) {
        int s = csrc[i];
        float ea = asrc[s * 4 + ha] + ad_a;
        float eb = asrc[s * 4 + hb] + ad_b;
        ea = (ea > 0.f) ? ea : 0.2f * ea;
        eb = (eb > 0.f) ? eb : 0.2f * eb;
        float wa = __expf(ea - ma), wb = __expf(eb - mb);
        da += wa; db += wb;
        ushort4 va = *(const ushort4*)(h + (size_t)s * 512 + c0);
        ushort4 vb = *(const ushort4*)(h + (size_t)s * 512 + 256 + c0);
        aa[0] += wa * bf16_tof(va.x); aa[1] += wa * bf16_tof(va.y);
        aa[2] += wa * bf16_tof(va.z); aa[3] += wa * bf16_tof(va.w);
        ab[0] += wb * bf16_tof(vb.x); ab[1] += wb * bf16_tof(vb.y);
        ab[2] += wb * bf16_tof(vb.z); ab[3] += wb * bf16_tof(vb.w);
    }
    float ia = 1.f / (da + 1e-16f), ib = 1.f / (db + 1e-16f);
    float s4[4];
    #pragma unroll
    for (int j = 0; j < 4; ++j) s4[j] = aa[j] * ia + ab[j] * ib;
    float p4[4];
    #pragma unroll
    for (int j = 0; j < 4; ++j) p4[j] = __shfl_xor(s4[j], 32, 64);
    if (lane < 32) {
        float4 b4 = *(const float4*)(bias + c0);
        ushort4 l4 = *(const ushort4*)(lin + (size_t)d * 128 + c0);
        float4 o;
        o.x = 0.25f * (s4[0] + p4[0]) + b4.x + bf16_tof(l4.x);
        o.y = 0.25f * (s4[1] + p4[1]) + b4.y + bf16_tof(l4.y);
        o.z = 0.25f * (s4[2] + p4[2]) + b4.z + bf16_tof(l4.z);
        o.w = 0.25f * (s4[3] + p4[3]) + b4.w + bf16_tof(l4.w);
        *(float4*)(out + (size_t)d * 128 + c0) = o;
    }
}

// ---------------------------------------------------------------------------

extern "C" void kernel_launch(void* const* d_in, const int* in_sizes, int n_in,
                              void* d_out, int out_size, void* d_ws, size_t ws_size,
                              hipStream_t stream)
{
    const float* x   = (const float*)d_in[0];
    const int*   ei  = (const int*)d_in[1];
    const float* W0  = (const float*)d_in[2];
    const float* as0 = (const float*)d_in[3];
    const float* ad0 = (const float*)d_in[4];
    const float* b0  = (const float*)d_in[5];
    const float* lw0 = (const float*)d_in[6];
    const float* lb0 = (const float*)d_in[7];
    const float* W1  = (const float*)d_in[8];
    const float* as1 = (const float*)d_in[9];
    const float* ad1 = (const float*)d_in[10];
    const float* b1  = (const float*)d_in[11];
    const float* lw1 = (const float*)d_in[12];
    const float* lb1 = (const float*)d_in[13];
    const float* W2  = (const float*)d_in[14];
    const float* as2 = (const float*)d_in[15];
    const float* ad2 = (const float*)d_in[16];
    const float* b2  = (const float*)d_in[17];
    const float* lw2 = (const float*)d_in[18];
    const float* lb2 = (const float*)d_in[19];
    float* out = (float*)d_out;

    const int N = in_sizes[0] / 256;
    const int E = in_sizes[1] / 2;
    const int* esrc = ei;
    const int* edst = ei + E;

    const int gm = (N + 127) / 128;          // 391
    const int gmp = ((gm + 7) / 8) * 8;      // 392 (XCD multiple)
    const size_t Agroups = (size_t)gm * 8;   // 16-row groups in padded A

    // ---- workspace layout ----
    char* p = (char*)d_ws;
    ushort* act_hi = (ushort*)p; p += Agroups * 8 * 512 * 2;   // packed, 25.6 MB
    ushort* act_lo = (ushort*)p; p += Agroups * 8 * 512 * 2;
    ushort* h      = (ushort*)p; p += (size_t)N * 512 * 2;
    ushort* lin    = (ushort*)p; p += (size_t)N * 256 * 2;
    float*  as_a   = (float*)p;  p += (size_t)N * 4 * 4;
    float*  ad_a   = (float*)p;  p += (size_t)N * 4 * 4;
    float*  as_b   = (float*)p;  p += (size_t)N * 4 * 4;
    float*  ad_b   = (float*)p;  p += (size_t)N * 4 * 4;
    ushort* B0h = (ushort*)p; p += (size_t)32 * 8 * 512 * 2;   // 512 rows packed
    ushort* B0l = (ushort*)p; p += (size_t)32 * 8 * 512 * 2;
    ushort* B1h = (ushort*)p; p += (size_t)32 * 8 * 512 * 2;
    ushort* B1l = (ushort*)p; p += (size_t)32 * 8 * 512 * 2;
    ushort* B2h = (ushort*)p; p += (size_t)40 * 8 * 512 * 2;   // 640 rows packed
    ushort* B2l = (ushort*)p; p += (size_t)40 * 8 * 512 * 2;
    float* vsd0 = (float*)p; p += 256 * 8 * 4;
    float* vsd1 = (float*)p; p += 256 * 8 * 4;
    float* vsd2 = (float*)p; p += 256 * 8 * 4;
    unsigned int* amax = (unsigned int*)p;      // 12 slots (4 per layer)
    int* deg    = (int*)(amax + 12);
    int* off    = deg + N;
    int* cursor = off + N + 1;
    int* csrc   = cursor + N;

    // ---- zero amax + deg + off + cursor in one memset ----
    hipMemsetAsync(amax, 0, sizeof(int) * (size_t)(3 * N + 13), stream);

    // ---- CSR build ----
    int egrid = (E + 255) / 256;
    degree_kernel<<<egrid, 256, 0, stream>>>(edst, deg, E);
    scan_kernel<<<1, 1024, 0, stream>>>(deg, off, N);
    scatter_kernel<<<egrid, 256, 0, stream>>>(esrc, edst, off, cursor, csrc, E);

    // ---- merged weight prep (packed B + att folds) ----
    wprep_kernel<<<1676, 256, 0, stream>>>(W0, lw0, W1, lw1, W2, lw2,
                                           B0h, B0l, B1h, B1l, B2h, B2l,
                                           as0, ad0, as1, ad1, as2, ad2,
                                           vsd0, vsd1, vsd2);

    int g4 = (N + 3) / 4;

    // ---- x -> packed act + layer-0 attention scalars ----
    split_att_kernel<<<g4, 256, 0, stream>>>(x, vsd0, act_hi, act_lo, as_a, ad_a, N);
    amax_kernel<<<32, 256, 0, stream>>>(as_a, amax + 0, N);

    // ---- layer 0 ----
    gemm_mfma_kernel<<<gmp * 4, 256, 0, stream>>>(act_hi, act_lo, B0h, B0l, h, 256, lin, lb0, gm, N, 512);
    agg01_kernel<<<g4, 256, 0, stream>>>(h, as_a, ad_a, amax + 0, off, csrc, lin, b0,
                                         act_hi, act_lo, vsd1, as_b, ad_b, N);
    amax_kernel<<<32, 256, 0, stream>>>(as_b, amax + 4, N);

    // ---- layer 1 ----
    gemm_mfma_kernel<<<gmp * 4, 256, 0, stream>>>(act_hi, act_lo, B1h, B1l, h, 256, lin, lb1, gm, N, 512);
    agg01_kernel<<<g4, 256, 0, stream>>>(h, as_b, ad_b, amax + 4, off, csrc, lin, b1,
                                         act_hi, act_lo, vsd2, as_a, ad_a, N);
    amax_kernel<<<32, 256, 0, stream>>>(as_a, amax + 8, N);

    // ---- layer 2 ----
    gemm_mfma_kernel<<<gmp * 5, 256, 0, stream>>>(act_hi, act_lo, B2h, B2l, h, 512, lin, lb2, gm, N, 640);
    agg2_kernel<<<g4, 256, 0, stream>>>(h, as_a, ad_a, amax + 8, off, csrc, lin, b2, out, N);
}